// Round 9
// baseline (214.370 us; speedup 1.0000x reference)
//
#include <hip/hip_runtime.h>

#define CODEBOOK 1024
#define NGROUPS  8
#define CPG      128
#define Bn 32
#define Cn 256
#define Hn 32
#define Wn 32

#define ZQ_OFF   0
#define LOSS_OFF (Bn*Cn*Hn*Wn)      /* 8388608 */
#define IDX_OFF  (LOSS_OFF + 3)     /* 8388611 */

// ------------------------------------------------ A: codebook + norms (fused)
// VERBATIM from round-6 (validated): k-ascending FMA chain per output,
// fused |c|^2 with the exact shfl_down(32..1) order.
__global__ __launch_bounds__(64) void prologue_cb(const float* __restrict__ emb,
                                                  const float* __restrict__ proj,
                                                  float* __restrict__ cb,
                                                  float* __restrict__ norms,
                                                  double* __restrict__ lacc,
                                                  int* __restrict__ counter) {
    __shared__ float embrow[Cn];
    const int l = threadIdx.x;        // 0..63
    const int i = blockIdx.x;         // codebook row 0..1023
    if (i == 0 && l == 0) { lacc[0] = 0.0; counter[0] = 0; }
    *(float4*)&embrow[l * 4] = *(const float4*)(emb + (size_t)i * Cn + l * 4);
    __syncthreads();
    const float* p0 = proj + (size_t)(4 * l + 0) * Cn;
    const float* p1 = proj + (size_t)(4 * l + 1) * Cn;
    const float* p2 = proj + (size_t)(4 * l + 2) * Cn;
    const float* p3 = proj + (size_t)(4 * l + 3) * Cn;
    float a0 = 0.f, a1 = 0.f, a2 = 0.f, a3 = 0.f;
    for (int kq = 0; kq < 64; ++kq) {
        float4 e  = ((const float4*)embrow)[kq];      // same-addr broadcast
        float4 q0 = *(const float4*)(p0 + kq * 4);
        float4 q1 = *(const float4*)(p1 + kq * 4);
        float4 q2 = *(const float4*)(p2 + kq * 4);
        float4 q3 = *(const float4*)(p3 + kq * 4);
        a0 = __builtin_fmaf(e.x, q0.x, a0); a0 = __builtin_fmaf(e.y, q0.y, a0);
        a0 = __builtin_fmaf(e.z, q0.z, a0); a0 = __builtin_fmaf(e.w, q0.w, a0);
        a1 = __builtin_fmaf(e.x, q1.x, a1); a1 = __builtin_fmaf(e.y, q1.y, a1);
        a1 = __builtin_fmaf(e.z, q1.z, a1); a1 = __builtin_fmaf(e.w, q1.w, a1);
        a2 = __builtin_fmaf(e.x, q2.x, a2); a2 = __builtin_fmaf(e.y, q2.y, a2);
        a2 = __builtin_fmaf(e.z, q2.z, a2); a2 = __builtin_fmaf(e.w, q2.w, a2);
        a3 = __builtin_fmaf(e.x, q3.x, a3); a3 = __builtin_fmaf(e.y, q3.y, a3);
        a3 = __builtin_fmaf(e.z, q3.z, a3); a3 = __builtin_fmaf(e.w, q3.w, a3);
    }
    float4 o; o.x = a0; o.y = a1; o.z = a2; o.w = a3;
    *(float4*)(cb + (size_t)i * Cn + 4 * l) = o;
    float s = o.x*o.x + o.y*o.y + o.z*o.z + o.w*o.w;
#pragma unroll
    for (int off = 32; off > 0; off >>= 1) s += __shfl_down(s, off);
    if (l == 0) norms[i] = s;
}

// ------------------------------------------------------------- B: main VQ
// lane = token (64 tokens/block), 8 waves x 16 codes. z staged ONCE into LDS
// (zl[256][68], padded); cb operands wave-uniform (readfirstlane wave id) ->
// SGPR path; GEMM inner loop = 1 LDS b32 z-read + 16 FMA with scalar sources.
// All validated numeric chains preserved: k-ascending single-acc FMA per
// (token,code); numpy-pairwise |z|^2 (8 thr/token, acc a sums k==a mod 8
// ascending, exact shfl_xor tree); d = fl(fl(Z+C)-2T); first-min ties
// (ci ascending within wave, wave ascending across); r6-validated loss path.
__global__ __launch_bounds__(512, 2) void vq_main(const float* __restrict__ z,
                                                  const float* __restrict__ cb,
                                                  const float* __restrict__ norms,
                                                  float* __restrict__ out,
                                                  double* __restrict__ lacc,
                                                  int* __restrict__ counter) {
    __shared__ float zl[256][68];     // [k][tok], pad 68 -> conflict-free both axes
    __shared__ float zfin[64];
    __shared__ float red_d[8][64];    // also reused as rr[512] for loss reduce
    __shared__ int   red_c[8][64];
    __shared__ int   bestidx[64];

    const int t   = threadIdx.x;
    // XCD sibling swizzle (validated r3): g-siblings of a (b,ht) pair land on
    // the same XCD -> shared z/cb slabs L2-resident.
    const int bid = blockIdx.x;
    const int r   = bid & 7;
    const int q   = bid >> 3;
    const int g   = q & 7;
    const int s   = ((q >> 3) << 3) | r;
    const int ht  = s & 1;
    const int b   = s >> 1;
    const int h0  = ht * 16;
    const int w0  = g * 4;

    const float* zb  = z  + (size_t)b * (Cn * Hn * Wn);
    const float* cbg = cb + (size_t)g * CPG * Cn;
    const int lane = t & 63;          // token within block

    // ---- stage z once: 512 thr x 8 float4 = 256 k x 64 tok
#pragma unroll
    for (int m = 0; m < 8; ++m) {
        int id = t + m * 512;                 // 0..4095
        int k = id >> 4, i = id & 15;
        *(float4*)&zl[k][i * 4] =
            *(const float4*)(zb + (size_t)k * (Hn * Wn) + (h0 + i) * Wn + w0);
    }
    __syncthreads();

    // ---- |z|^2: 8 threads/token; acc a8 sums k == a8 (mod 8), ascending ->
    // exactly numpy's 8-accumulator pairwise; shfl_xor tree = exact combine.
    {
#pragma clang fp contract(off)
        const int tk8 = t >> 3, a8 = t & 7;
        float zA = 0.f, zB = 0.f;
        for (int j = 0; j < 16; ++j) { float v = zl[a8 + 8 * j][tk8];       zA += v * v; }
        for (int j = 0; j < 16; ++j) { float v = zl[128 + a8 + 8 * j][tk8]; zB += v * v; }
        float s1 = zA + __shfl_xor(zA, 1);
        float s2 = s1 + __shfl_xor(s1, 2);
        float zh0 = s2 + __shfl_xor(s2, 4);   // ((r0+r1)+(r2+r3))+((r4+r5)+(r6+r7))
        float t1 = zB + __shfl_xor(zB, 1);
        float t2 = t1 + __shfl_xor(t1, 2);
        float zh1 = t2 + __shfl_xor(t2, 4);
        if (a8 == 0) zfin[tk8] = zh0 + zh1;
    }
    __syncthreads();

    // ---- GEMM: wave wv owns codes [16wv, 16wv+16); cb addresses wave-uniform
    const int wv = __builtin_amdgcn_readfirstlane((int)threadIdx.x) >> 6; // 0..7
    const float* __restrict__ cbw = cbg + (size_t)(wv * 16) * Cn;

    float acc[16];
#pragma unroll
    for (int ci = 0; ci < 16; ++ci) acc[ci] = 0.f;

#pragma unroll 2
    for (int k = 0; k < Cn; k += 4) {
        float z0 = zl[k + 0][lane];
        float z1 = zl[k + 1][lane];
        float z2 = zl[k + 2][lane];
        float z3 = zl[k + 3][lane];
#pragma unroll
        for (int ci = 0; ci < 16; ++ci) {
            float4 c4 = *(const float4*)(cbw + (size_t)ci * Cn + k); // uniform
            acc[ci] = __builtin_fmaf(z0, c4.x, acc[ci]);
            acc[ci] = __builtin_fmaf(z1, c4.y, acc[ci]);
            acc[ci] = __builtin_fmaf(z2, c4.z, acc[ci]);
            acc[ci] = __builtin_fmaf(z3, c4.w, acc[ci]);
        }
    }

    // ---- per-wave argmin over its 16 codes (ascending -> first-min)
    {
        float Z = zfin[lane];
        float nvv[16];
#pragma unroll
        for (int q2 = 0; q2 < 4; ++q2)
            *(float4*)&nvv[q2 * 4] =
                *(const float4*)(norms + g * CPG + wv * 16 + q2 * 4); // uniform
        float bd = __builtin_inff();
        int   bc = 0;
#pragma unroll
        for (int ci = 0; ci < 16; ++ci) {
            float ss = Z + nvv[ci];               // fl(Z + C_i)
            float d  = ss - 2.0f * acc[ci];       // fl(S - 2T), 2T exact
            if (d < bd) { bd = d; bc = wv * 16 + ci; }
        }
        red_d[wv][lane] = bd;
        red_c[wv][lane] = bc;
    }
    __syncthreads();

    // ---- cross-wave argmin, ascending wave order -> global first-min
    if (t < 64) {
        float bd = red_d[0][t];
        int   bc = red_c[0][t];
#pragma unroll
        for (int w2 = 1; w2 < 8; ++w2) {
            float d = red_d[w2][t];
            if (d < bd) { bd = d; bc = red_c[w2][t]; }
        }
        int gidx = g * CPG + bc;
        bestidx[t] = gidx;
        out[IDX_OFF + b * (Hn * Wn) + (h0 + (t >> 2)) * Wn + (w0 + (t & 3))] = (float)gidx;
    }
    __syncthreads();

    // ---- zq write (NCHW, float4 along w; z re-read from LDS) + loss
    float lsum = 0.f;
    const size_t zbase = (size_t)b * (Cn * Hn * Wn);
#pragma unroll
    for (int m = 0; m < 8; ++m) {
        int id = t + m * 512;                     // 0..4095
        int c = id >> 4, i = id & 15;
        float4 zv = *(const float4*)&zl[c][i * 4];
        float q0 = cb[(size_t)bestidx[i * 4 + 0] * Cn + c];
        float q1 = cb[(size_t)bestidx[i * 4 + 1] * Cn + c];
        float q2 = cb[(size_t)bestidx[i * 4 + 2] * Cn + c];
        float q3 = cb[(size_t)bestidx[i * 4 + 3] * Cn + c];
        float4 o; o.x = q0; o.y = q1; o.z = q2; o.w = q3;
        *(float4*)(out + ZQ_OFF + zbase + (size_t)c * (Hn * Wn) + (h0 + i) * Wn + w0) = o;
        float d0 = q0 - zv.x, d1 = q1 - zv.y, d2 = q2 - zv.z, d3 = q3 - zv.w;
        lsum = __builtin_fmaf(d0, d0, lsum);
        lsum = __builtin_fmaf(d1, d1, lsum);
        lsum = __builtin_fmaf(d2, d2, lsum);
        lsum = __builtin_fmaf(d3, d3, lsum);
    }
    __syncthreads();
    float* rr = &red_d[0][0];                     // reuse as float[512]
    rr[t] = lsum;
    __syncthreads();
    for (int s2 = 256; s2 > 0; s2 >>= 1) {
        if (t < s2) rr[t] += rr[t + s2];
        __syncthreads();
    }
    // fused finalize: last block to arrive writes the 3 loss scalars (r6 ✓)
    if (t == 0) {
        atomicAdd(lacc, (double)rr[0]);           // device-scope
        __threadfence();
        int done = atomicAdd(counter, 1);
        if (done == (int)gridDim.x - 1) {
            double tot = atomicAdd(lacc, 0.0);    // coherent read-back
            float M    = (float)(tot / (double)(Bn * Cn * Hn * Wn));
            float comm = 0.25f * M;
            out[LOSS_OFF + 0] = comm + M;   // loss
            out[LOSS_OFF + 1] = comm;       // commitment_loss
            out[LOSS_OFF + 2] = M;          // codebook_loss
        }
    }
}

extern "C" void kernel_launch(void* const* d_in, const int* in_sizes, int n_in,
                              void* d_out, int out_size, void* d_ws, size_t ws_size,
                              hipStream_t stream) {
    (void)in_sizes; (void)n_in; (void)out_size; (void)ws_size;
    const float* z    = (const float*)d_in[0];
    const float* emb  = (const float*)d_in[1];
    const float* proj = (const float*)d_in[2];
    float* out = (float*)d_out;

    char*   ws      = (char*)d_ws;
    float*  cb      = (float*)ws;                          // 1 MB
    float*  norms   = (float*)(ws + 1048576);              // 4 KB
    double* lacc    = (double*)(ws + 1048576 + 4096);      // 8 B
    int*    counter = (int*)(ws + 1048576 + 4096 + 8);     // 4 B

    prologue_cb<<<CODEBOOK, 64, 0, stream>>>(emb, proj, cb, norms, lacc, counter);
    vq_main    <<<Bn*2*NGROUPS, 512, 0, stream>>>(z, cb, norms, out, lacc, counter);
}